// Round 5
// baseline (241770.435 us; speedup 1.0000x reference)
//
#include <hip/hip_runtime.h>
#include <math.h>

#define D 128
#define NH 16
#define HD 8
#define NLAYER 16
#define V 17
#define L 1024
#define BOSX 16
#define NHEAL 31
#define NWG 128

struct P {
  const int* tokens;
  const float *emb, *pos, *ln1_s, *ln1_b, *wqkv, *bqkv, *wo, *bo;
  const float *ln2_s, *ln2_b, *w1, *b1, *w2, *b2, *lnf_s, *lnf_b, *hw, *hb;
  float *h, *qbuf, *kc, *vc, *ll_;
  int *lat, *heal_row, *bounds;
  int *barc;  // [0]=arrive counter (monotonic), [32]=phase
  float *logits, *out_tok;
};

// ---- fast grid barrier: monotonic counter + phase flag, agent scope ----
__device__ __forceinline__ void gridBar(int* cnt, int* phs, int& b) {
  __syncthreads();
  if (threadIdx.x == 0) {
    __threadfence();  // agent-scope fence: make this WG's writes visible
    int prev = __hip_atomic_fetch_add(cnt, 1, __ATOMIC_RELAXED, __HIP_MEMORY_SCOPE_AGENT);
    if (prev == b * NWG + (NWG - 1)) {
      __hip_atomic_store(phs, b + 1, __ATOMIC_RELEASE, __HIP_MEMORY_SCOPE_AGENT);
    } else {
      while (__hip_atomic_load(phs, __ATOMIC_ACQUIRE, __HIP_MEMORY_SCOPE_AGENT) < b + 1)
        __builtin_amdgcn_s_sleep(2);
    }
    __threadfence();  // acquire side: invalidate caches before reading others' data
  }
  b += 1;
  __syncthreads();
}

__device__ __forceinline__ float geluf(float a) {
  float cgv = 0.7978845608028654f * (a + 0.044715f * a * a * a);
  cgv = fminf(fmaxf(cgv, -15.f), 15.f);
  float e = __expf(2.f * cgv);
  return 0.5f * a * (1.f + (e - 1.f) / (e + 1.f));
}

// LayerNorm of in[0..127] -> out[0..127]; 256 threads; trailing barrier.
__device__ void lnorm(const float* __restrict__ s, const float* __restrict__ b,
                      const float* in, float* out, float* red) {
  int t = threadIdx.x;
  float v = (t < D) ? in[t] : 0.f;
  float sm = v;
#pragma unroll
  for (int o = 32; o; o >>= 1) sm += __shfl_xor(sm, o, 64);
  if ((t & 63) == 0) red[t >> 6] = sm;
  __syncthreads();
  float mean = (red[0] + red[1] + red[2] + red[3]) * (1.f / 128.f);
  float d = (t < D) ? (v - mean) : 0.f;
  float vs = d * d;
#pragma unroll
  for (int o = 32; o; o >>= 1) vs += __shfl_xor(vs, o, 64);
  if ((t & 63) == 0) red[4 + (t >> 6)] = vs;
  __syncthreads();
  float rstd = rsqrtf((red[4] + red[5] + red[6] + red[7]) * (1.f / 128.f) + 1e-5f);
  if (t < D) out[t] = d * rstd * s[t] + b[t];
  __syncthreads();
}

// qkv = x @ w[128x384] + b for one row; threads 0..191 take cols (t, t+192)
__device__ void qkvRow(const float* __restrict__ w, const float* __restrict__ b,
                       int row, float* q, float* k, float* v, const float* x) {
  int t = threadIdx.x;
  if (t < 192) {
    int c0 = t, c1 = t + 192;
    const float* w0 = w + c0;
    const float* w1 = w + c1;
    float a0 = 0.f, a1 = 0.f;
#pragma unroll 16
    for (int d = 0; d < D; ++d) {
      float xv = x[d];
      a0 += xv * w0[d * 384];
      a1 += xv * w1[d * 384];
    }
    a0 += b[c0]; a1 += b[c1];
    if (c0 < 128) q[row * D + c0] = a0;
    else          k[row * D + (c0 - 128)] = a0;
    if (c1 < 256) k[row * D + (c1 - 128)] = a1;
    else          v[row * D + (c1 - 256)] = a1;
  }
}

// embed + LN1 + qkv(layer 0) for one row
__device__ void rowPre(int row, const P& p, float* hrowS, float* xS, float* redS) {
  int t = threadIdx.x;
  if (t < D) {
    float hv = p.emb[p.lat[row] * D + t] + p.pos[row * D + t];
    p.h[row * D + t] = hv;
    hrowS[t] = hv;
  }
  __syncthreads();
  lnorm(p.ln1_s, p.ln1_b, hrowS, xS, redS);
  qkvRow(p.wqkv, p.bqkv, row, p.qbuf, p.kc, p.vc, xS);
}

// attention(l)+proj+res+LN2+FFN+res; then LN1+qkv(l+1) or LNf+head
__device__ void rowMain(int row, int l, const P& p, float* hrowS, float* xS,
                        float* obufS, float* fS, float* padS, float* redS) {
  int t = threadIdx.x;
  if (t < D) hrowS[t] = p.h[row * D + t];
  // ---- attention: (head = t>>4, lane = t&15), softmax without max-sub (scores tiny)
  {
    const float* kcl = p.kc + (size_t)l * L * D;
    const float* vcl = p.vc + (size_t)l * L * D;
    int head = t >> 4, lane = t & 15;
    const float4* qp = (const float4*)(p.qbuf + row * D + head * HD);
    float4 q0 = qp[0], q1 = qp[1];
    float sum = 0.f;
    float a0=0,a1=0,a2=0,a3=0,a4=0,a5=0,a6=0,a7=0;
#pragma unroll 2
    for (int key = lane; key <= row; key += 16) {
      const float4* kp = (const float4*)(kcl + key * D + head * HD);
      float4 k0 = kp[0], k1 = kp[1];
      float sc = q0.x*k0.x + q0.y*k0.y + q0.z*k0.z + q0.w*k0.w
               + q1.x*k1.x + q1.y*k1.y + q1.z*k1.z + q1.w*k1.w;
      float pr = __expf(sc * 0.35355339059327376f);
      const float4* vp = (const float4*)(vcl + key * D + head * HD);
      float4 v0 = vp[0], v1 = vp[1];
      sum += pr;
      a0 += pr*v0.x; a1 += pr*v0.y; a2 += pr*v0.z; a3 += pr*v0.w;
      a4 += pr*v1.x; a5 += pr*v1.y; a6 += pr*v1.z; a7 += pr*v1.w;
    }
#pragma unroll
    for (int o = 1; o < 16; o <<= 1) {
      sum += __shfl_xor(sum, o, 16);
      a0 += __shfl_xor(a0, o, 16); a1 += __shfl_xor(a1, o, 16);
      a2 += __shfl_xor(a2, o, 16); a3 += __shfl_xor(a3, o, 16);
      a4 += __shfl_xor(a4, o, 16); a5 += __shfl_xor(a5, o, 16);
      a6 += __shfl_xor(a6, o, 16); a7 += __shfl_xor(a7, o, 16);
    }
    if (lane == 0) {
      float inv = 1.f / sum;
      obufS[head * HD + 0] = a0 * inv; obufS[head * HD + 1] = a1 * inv;
      obufS[head * HD + 2] = a2 * inv; obufS[head * HD + 3] = a3 * inv;
      obufS[head * HD + 4] = a4 * inv; obufS[head * HD + 5] = a5 * inv;
      obufS[head * HD + 6] = a6 * inv; obufS[head * HD + 7] = a7 * inv;
    }
  }
  __syncthreads();
  // ---- proj (split-d over 2 halves) + residual ----
  {
    int half = t >> 7, c = t & 127;
    const float* wp = p.wo + (size_t)l * D * D + c;
    float acc = 0.f;
    int d0 = half * 64;
#pragma unroll 8
    for (int d = d0; d < d0 + 64; ++d) acc += obufS[d] * wp[d * D];
    padS[half * 128 + c] = acc;
  }
  __syncthreads();
  if (t < D) {
    float hv = hrowS[t] + padS[t] + padS[128 + t] + p.bo[l * D + t];
    hrowS[t] = hv;
    p.h[row * D + t] = hv;
  }
  __syncthreads();
  lnorm(p.ln2_s + l * D, p.ln2_b + l * D, hrowS, xS, redS);
  // ---- FF1 + gelu: cols (t, t+256) ----
  {
    const float* w1p = p.w1 + (size_t)l * D * 512;
    float acc0 = 0.f, acc1 = 0.f;
#pragma unroll 16
    for (int d = 0; d < D; ++d) {
      float xv = xS[d];
      acc0 += xv * w1p[d * 512 + t];
      acc1 += xv * w1p[d * 512 + t + 256];
    }
    fS[t]       = geluf(acc0 + p.b1[l * 512 + t]);
    fS[t + 256] = geluf(acc1 + p.b1[l * 512 + t + 256]);
  }
  __syncthreads();
  // ---- FF2 (split-d over 2 halves of 256) + residual ----
  {
    int half = t >> 7, c = t & 127;
    const float* w2p = p.w2 + (size_t)l * 512 * D + c;
    float acc = 0.f;
    int d0 = half * 256;
#pragma unroll 8
    for (int d = d0; d < d0 + 256; ++d) acc += fS[d] * w2p[d * D];
    padS[half * 128 + c] = acc;
  }
  __syncthreads();
  if (t < D) {
    float hv = hrowS[t] + padS[t] + padS[128 + t] + p.b2[l * D + t];
    hrowS[t] = hv;
    p.h[row * D + t] = hv;
  }
  __syncthreads();
  if (l < NLAYER - 1) {
    lnorm(p.ln1_s + (l + 1) * D, p.ln1_b + (l + 1) * D, hrowS, xS, redS);
    qkvRow(p.wqkv + (size_t)(l + 1) * D * 384, p.bqkv + (l + 1) * 384, row,
           p.qbuf, p.kc + (size_t)(l + 1) * L * D, p.vc + (size_t)(l + 1) * L * D, xS);
  } else {
    lnorm(p.lnf_s, p.lnf_b, hrowS, xS, redS);
    if (t < V * 8) {
      int col = t >> 3, seg = t & 7;
      float acc = 0.f;
      int d0 = seg * 16;
#pragma unroll
      for (int d = d0; d < d0 + 16; ++d) acc += xS[d] * p.hw[d * V + col];
      padS[t] = acc;
    }
    __syncthreads();
    if (t < V) {
      float a = padS[t*8] + padS[t*8+1] + padS[t*8+2] + padS[t*8+3]
              + padS[t*8+4] + padS[t*8+5] + padS[t*8+6] + padS[t*8+7];
      p.logits[row * V + t] = a + p.hb[t];
    }
    __syncthreads();
  }
}

// ---- init: lat + barrier state (separate dispatch => flushed before kMega) ----
__global__ void kInit(const int* __restrict__ tokens, int* __restrict__ lat,
                      int* __restrict__ barc) {
  int i = blockIdx.x * blockDim.x + threadIdx.x;
  if (i == 0) lat[0] = BOSX;
  if (i < L) lat[i + 1] = tokens[i];
  if (i < 64) barc[i] = 0;
}

__global__ void kMega(P p) {
  __shared__ float hrowS[D];
  __shared__ float xS[D];
  __shared__ float obufS[D];
  __shared__ float fS[512];
  __shared__ float padS[256];
  __shared__ float redS[8];
  __shared__ float sortS[L];
  __shared__ int cntS[257];
  int wg = blockIdx.x, t = threadIdx.x;
  int gid = wg * 256 + t;
  int* barCnt = p.barc;
  int* barPhs = p.barc + 32;
  int b = 0;

  // ---- phase A: full pass over 1024 rows ----
  for (int row = wg; row < L; row += NWG) rowPre(row, p, hrowS, xS, redS);
  gridBar(barCnt, barPhs, b);
  for (int l = 0; l < NLAYER; ++l) {
    for (int row = wg; row < L; row += NWG)
      rowMain(row, l, p, hrowS, xS, obufS, fS, padS, redS);
    gridBar(barCnt, barPhs, b);
  }

  // ---- log-likelihoods ----
  if (gid < L) {
    const float* r = p.logits + gid * V;
    float m = r[0];
#pragma unroll
    for (int v = 1; v < V; ++v) m = fmaxf(m, r[v]);
    float s = 0.f;
#pragma unroll
    for (int v = 0; v < V; ++v) s += expf(r[v] - m);
    p.ll_[gid] = r[p.lat[gid + 1]] - (m + logf(s));
  }
  gridBar(barCnt, barPhs, b);

  // ---- sort + quantile + heal list + bounds + heal 0 (WG 0 only) ----
  if (wg == 0) {
    for (int i = t; i < L; i += 256) sortS[i] = p.ll_[i];
    __syncthreads();
    for (int ksz = 2; ksz <= L; ksz <<= 1) {
      for (int j = ksz >> 1; j; j >>= 1) {
        for (int i = t; i < L; i += 256) {
          int l2 = i ^ j;
          if (l2 > i) {
            bool up = ((i & ksz) == 0);
            float a = sortS[i], bb = sortS[l2];
            if ((a > bb) == up) { sortS[i] = bb; sortS[l2] = a; }
          }
        }
        __syncthreads();
      }
    }
    if (t == 0) {
      double frac = 0.03 * 1023.0 - 30.0;  // 0.69
      redS[0] = (float)((double)sortS[30] + frac * ((double)sortS[31] - (double)sortS[30]));
    }
    __syncthreads();
    float val = redS[0];
    float lv[4];
    int loc[4], cnt = 0;
#pragma unroll
    for (int j = 0; j < 4; ++j) lv[j] = p.ll_[t * 4 + j];
#pragma unroll
    for (int j = 0; j < 4; ++j)
      if (lv[j] < val) loc[cnt++] = t * 4 + j;
    cntS[t] = cnt;
    __syncthreads();
    if (t == 0) {
      int run = 0;
      for (int i = 0; i < 256; ++i) { int c = cntS[i]; cntS[i] = run; run += c; }
      cntS[256] = run;
    }
    __syncthreads();
    int base = cntS[t];
    for (int j = 0; j < cnt; ++j)
      if (base + j < NHEAL) p.heal_row[base + j] = loc[j];
    __syncthreads();
    if (t == 0) {
      int c = cntS[256];
      if (c > NHEAL) c = NHEAL;
      for (int k = 0; k < NHEAL; ++k) {
        if (k < c) {
          p.bounds[2 * k] = (k == 0) ? 1 : (p.heal_row[k - 1] + 1);
          p.bounds[2 * k + 1] = (k == 0) ? 0 : p.heal_row[k];
        } else {
          p.heal_row[k] = -1;
          p.bounds[2 * k] = 1;
          p.bounds[2 * k + 1] = 0;
        }
      }
      p.bounds[2 * NHEAL] = (c > 0) ? (p.heal_row[c - 1] + 1) : L;
      p.bounds[2 * NHEAL + 1] = L - 1;
      // heal 0 from phase-A logits
      if (c > 0) {
        int r = p.heal_row[0];
        const float* rowp = p.logits + r * V;
        int best = 0; float bv = rowp[0];
        for (int v = 1; v < BOSX; ++v)
          if (rowp[v] > bv) { bv = rowp[v]; best = v; }
        p.lat[r + 1] = best;
      }
    }
  }
  gridBar(barCnt, barPhs, b);

  // ---- chunks 1..30 (heal) and NHEAL (tail, no heal) ----
  for (int k = 1; k <= NHEAL; ++k) {
    int cs = p.bounds[2 * k], ce = p.bounds[2 * k + 1];
    if (cs <= ce) {
      for (int row = cs + wg; row <= ce; row += NWG) rowPre(row, p, hrowS, xS, redS);
      gridBar(barCnt, barPhs, b);
      for (int l = 0; l < NLAYER; ++l) {
        for (int row = cs + wg; row <= ce; row += NWG)
          rowMain(row, l, p, hrowS, xS, obufS, fS, padS, redS);
        gridBar(barCnt, barPhs, b);
      }
      if (k < NHEAL && wg == 0 && t == 0) {
        int r = p.heal_row[k];
        if (r >= 0) {
          const float* rowp = p.logits + r * V;
          int best = 0; float bv = rowp[0];
          for (int v = 1; v < BOSX; ++v)
            if (rowp[v] > bv) { bv = rowp[v]; best = v; }
          p.lat[r + 1] = best;
        }
      }
      gridBar(barCnt, barPhs, b);
    }
  }

  // ---- tokens out ----
  if (gid < L) p.out_tok[gid] = (float)p.lat[gid + 1];
}

extern "C" void kernel_launch(void* const* d_in, const int* in_sizes, int n_in,
                              void* d_out, int out_size, void* d_ws, size_t ws_size,
                              hipStream_t stream) {
  P prm;
  prm.tokens = (const int*)d_in[0];
  prm.emb    = (const float*)d_in[1];
  prm.pos    = (const float*)d_in[2];
  prm.ln1_s  = (const float*)d_in[3];
  prm.ln1_b  = (const float*)d_in[4];
  prm.wqkv   = (const float*)d_in[5];
  prm.bqkv   = (const float*)d_in[6];
  prm.wo     = (const float*)d_in[7];
  prm.bo     = (const float*)d_in[8];
  prm.ln2_s  = (const float*)d_in[9];
  prm.ln2_b  = (const float*)d_in[10];
  prm.w1     = (const float*)d_in[11];
  prm.b1     = (const float*)d_in[12];
  prm.w2     = (const float*)d_in[13];
  prm.b2     = (const float*)d_in[14];
  prm.lnf_s  = (const float*)d_in[15];
  prm.lnf_b  = (const float*)d_in[16];
  prm.hw     = (const float*)d_in[17];
  prm.hb     = (const float*)d_in[18];

  float* ws = (float*)d_ws;
  prm.h    = ws;                       // L*D
  prm.qbuf = prm.h + L * D;            // L*D
  prm.kc   = prm.qbuf + L * D;         // NLAYER*L*D
  prm.vc   = prm.kc + NLAYER * L * D;  // NLAYER*L*D
  prm.ll_  = prm.vc + NLAYER * L * D;  // L
  prm.lat      = (int*)(prm.ll_ + L);  // 1025 (pad 1032)
  prm.heal_row = prm.lat + 1032;       // 32
  prm.bounds   = prm.heal_row + 32;    // 64
  prm.barc     = prm.bounds + 64;      // 64 (cnt @0, phase @32)

  prm.logits  = (float*)d_out;         // L*V
  prm.out_tok = prm.logits + L * V;    // L

  kInit<<<5, 256, 0, stream>>>(prm.tokens, prm.lat, prm.barc);

  void* args[] = { &prm };
  hipLaunchCooperativeKernel((const void*)kMega, dim3(NWG), dim3(256), args, 0, stream);
}

// Round 6
// 92749.786 us; speedup vs baseline: 2.6067x; 2.6067x over previous
//
#include <hip/hip_runtime.h>
#include <math.h>

#define D 128
#define NH 16
#define HD 8
#define NLAYER 16
#define V 17
#define L 1024
#define BOSX 16
#define NHEAL 31
#define NWG 128

struct P {
  const int* tokens;
  const float *emb, *pos, *ln1_s, *ln1_b, *wqkv, *bqkv, *wo, *bo;
  const float *ln2_s, *ln2_b, *w1, *b1, *w2, *b2, *lnf_s, *lnf_b, *hw, *hb;
  float *h, *qbuf, *kc, *vc, *ll_;
  int *lat, *heal_row, *bounds;
  int *barc;
  float *logits, *out_tok;
};

// ---- uncached (coherence-point) accessors: sc0/sc1, bypass L1+L2 ----
__device__ __forceinline__ float ldUf(const float* p) {
  return __hip_atomic_load((float*)p, __ATOMIC_RELAXED, __HIP_MEMORY_SCOPE_SYSTEM);
}
__device__ __forceinline__ float2 ldU2(const float* p) {
  union { double d; float2 f; } u;
  u.d = __hip_atomic_load((double*)p, __ATOMIC_RELAXED, __HIP_MEMORY_SCOPE_SYSTEM);
  return u.f;
}
__device__ __forceinline__ void stUf(float* p, float v) {
  __hip_atomic_store(p, v, __ATOMIC_RELAXED, __HIP_MEMORY_SCOPE_SYSTEM);
}
__device__ __forceinline__ int ldUi(const int* p) {
  return __hip_atomic_load((int*)p, __ATOMIC_RELAXED, __HIP_MEMORY_SCOPE_SYSTEM);
}
__device__ __forceinline__ void stUi(int* p, int v) {
  __hip_atomic_store(p, v, __ATOMIC_RELAXED, __HIP_MEMORY_SCOPE_SYSTEM);
}

// ---- light barrier: NO cache maintenance. Correct only because all
// cross-WG data in the heal phase moves via uncached (system-scope) ops. ----
__device__ __forceinline__ void barLight(int* cnt, int& b) {
  asm volatile("s_waitcnt vmcnt(0)" ::: "memory");  // drain this wave's stores
  __syncthreads();
  if (threadIdx.x == 0) {
    __hip_atomic_fetch_add(cnt, 1, __ATOMIC_RELAXED, __HIP_MEMORY_SCOPE_SYSTEM);
    int tgt = (b + 1) * NWG;
    while (__hip_atomic_load(cnt, __ATOMIC_RELAXED, __HIP_MEMORY_SCOPE_SYSTEM) < tgt)
      __builtin_amdgcn_s_sleep(1);
  }
  b += 1;
  __syncthreads();
}

// ---- full barrier: wb+inv via __threadfence, RELAXED spin (no per-poll inv!) ----
__device__ __forceinline__ void barFull(int* cnt, int& b) {
  asm volatile("s_waitcnt vmcnt(0)" ::: "memory");
  __syncthreads();
  if (threadIdx.x == 0) {
    __threadfence();  // writeback dirty L2 before publishing
    __hip_atomic_fetch_add(cnt, 1, __ATOMIC_RELAXED, __HIP_MEMORY_SCOPE_SYSTEM);
    int tgt = (b + 1) * NWG;
    while (__hip_atomic_load(cnt, __ATOMIC_RELAXED, __HIP_MEMORY_SCOPE_SYSTEM) < tgt)
      __builtin_amdgcn_s_sleep(1);
    __threadfence();  // invalidate so we see others' cached writes
  }
  b += 1;
  __syncthreads();
}

__device__ __forceinline__ float geluf(float a) {
  float cgv = 0.7978845608028654f * (a + 0.044715f * a * a * a);
  cgv = fminf(fmaxf(cgv, -15.f), 15.f);
  float e = __expf(2.f * cgv);
  return 0.5f * a * (1.f + (e - 1.f) / (e + 1.f));
}

__device__ void lnorm(const float* __restrict__ s, const float* __restrict__ b,
                      const float* in, float* out, float* red) {
  int t = threadIdx.x;
  float v = (t < D) ? in[t] : 0.f;
  float sm = v;
#pragma unroll
  for (int o = 32; o; o >>= 1) sm += __shfl_xor(sm, o, 64);
  if ((t & 63) == 0) red[t >> 6] = sm;
  __syncthreads();
  float mean = (red[0] + red[1] + red[2] + red[3]) * (1.f / 128.f);
  float d = (t < D) ? (v - mean) : 0.f;
  float vs = d * d;
#pragma unroll
  for (int o = 32; o; o >>= 1) vs += __shfl_xor(vs, o, 64);
  if ((t & 63) == 0) red[4 + (t >> 6)] = vs;
  __syncthreads();
  float rstd = rsqrtf((red[4] + red[5] + red[6] + red[7]) * (1.f / 128.f) + 1e-5f);
  if (t < D) out[t] = d * rstd * s[t] + b[t];
  __syncthreads();
}

// qkv for one row; K/V stores uncached when HEAL (cross-WG data)
template <bool HEAL>
__device__ void qkvRow(const float* __restrict__ w, const float* __restrict__ b,
                       int row, float* q, float* k, float* v, const float* x) {
  int t = threadIdx.x;
  if (t < 192) {
    int c0 = t, c1 = t + 192;
    const float* w0 = w + c0;
    const float* w1 = w + c1;
    float a0 = 0.f, a1 = 0.f;
#pragma unroll 16
    for (int d = 0; d < D; ++d) {
      float xv = x[d];
      a0 += xv * w0[d * 384];
      a1 += xv * w1[d * 384];
    }
    a0 += b[c0]; a1 += b[c1];
    if (c0 < 128) q[row * D + c0] = a0;  // qbuf: owner-only, cached
    else if (HEAL) stUf(&k[row * D + (c0 - 128)], a0);
    else           k[row * D + (c0 - 128)] = a0;
    if (c1 < 256) { if (HEAL) stUf(&k[row * D + (c1 - 128)], a1); else k[row * D + (c1 - 128)] = a1; }
    else          { if (HEAL) stUf(&v[row * D + (c1 - 256)], a1); else v[row * D + (c1 - 256)] = a1; }
  }
}

template <bool HEAL>
__device__ void rowPre(int row, const P& p, float* hrowS, float* xS, float* redS) {
  int t = threadIdx.x;
  if (t < D) {
    int tok = ldUi(&p.lat[row]);
    float hv = p.emb[tok * D + t] + p.pos[row * D + t];
    p.h[row * D + t] = hv;  // owner-only, cached
    hrowS[t] = hv;
  }
  __syncthreads();
  lnorm(p.ln1_s, p.ln1_b, hrowS, xS, redS);
  qkvRow<HEAL>(p.wqkv, p.bqkv, row, p.qbuf, p.kc, p.vc, xS);
}

template <bool HEAL>
__device__ void rowMain(int row, int l, int split, const P& p, float* hrowS, float* xS,
                        float* obufS, float* fS, float* padS, float* redS) {
  int t = threadIdx.x;
  if (t < D) hrowS[t] = p.h[row * D + t];
  // ---- attention: 16 lanes/head; scores tiny -> exp without max-sub ----
  {
    const float* kcl = p.kc + (size_t)l * L * D;
    const float* vcl = p.vc + (size_t)l * L * D;
    int head = t >> 4, lane = t & 15;
    const float4* qp = (const float4*)(p.qbuf + (size_t)row * D + head * HD);
    float4 q0 = qp[0], q1 = qp[1];
    float sum = 0.f;
    float a0=0,a1=0,a2=0,a3=0,a4=0,a5=0,a6=0,a7=0;
    int lim1 = HEAL ? ((split - 1 < row) ? split - 1 : row) : row;
    // cached segment: rows < split (phase-A K/V, never rewritten)
#pragma unroll 2
    for (int key = lane; key <= lim1; key += 16) {
      const float4* kp = (const float4*)(kcl + (size_t)key * D + head * HD);
      float4 k0 = kp[0], k1 = kp[1];
      float sc = q0.x*k0.x + q0.y*k0.y + q0.z*k0.z + q0.w*k0.w
               + q1.x*k1.x + q1.y*k1.y + q1.z*k1.z + q1.w*k1.w;
      float pr = __expf(sc * 0.35355339059327376f);
      const float4* vp = (const float4*)(vcl + (size_t)key * D + head * HD);
      float4 v0 = vp[0], v1 = vp[1];
      sum += pr;
      a0 += pr*v0.x; a1 += pr*v0.y; a2 += pr*v0.z; a3 += pr*v0.w;
      a4 += pr*v1.x; a5 += pr*v1.y; a6 += pr*v1.z; a7 += pr*v1.w;
    }
    if (HEAL) {
      // uncached segment: rows >= split (rewritten during healing)
      int start = split + ((lane - split) & 15);
#pragma unroll 2
      for (int key = start; key <= row; key += 16) {
        const float* kp = kcl + (size_t)key * D + head * HD;
        float2 ka = ldU2(kp), kb = ldU2(kp + 2), kc2 = ldU2(kp + 4), kd = ldU2(kp + 6);
        float sc = q0.x*ka.x + q0.y*ka.y + q0.z*kb.x + q0.w*kb.y
                 + q1.x*kc2.x + q1.y*kc2.y + q1.z*kd.x + q1.w*kd.y;
        float pr = __expf(sc * 0.35355339059327376f);
        const float* vp = vcl + (size_t)key * D + head * HD;
        float2 va = ldU2(vp), vb = ldU2(vp + 2), vc2 = ldU2(vp + 4), vd = ldU2(vp + 6);
        sum += pr;
        a0 += pr*va.x; a1 += pr*va.y; a2 += pr*vb.x; a3 += pr*vb.y;
        a4 += pr*vc2.x; a5 += pr*vc2.y; a6 += pr*vd.x; a7 += pr*vd.y;
      }
    }
#pragma unroll
    for (int o = 1; o < 16; o <<= 1) {
      sum += __shfl_xor(sum, o, 16);
      a0 += __shfl_xor(a0, o, 16); a1 += __shfl_xor(a1, o, 16);
      a2 += __shfl_xor(a2, o, 16); a3 += __shfl_xor(a3, o, 16);
      a4 += __shfl_xor(a4, o, 16); a5 += __shfl_xor(a5, o, 16);
      a6 += __shfl_xor(a6, o, 16); a7 += __shfl_xor(a7, o, 16);
    }
    if (lane == 0) {
      float inv = 1.f / sum;
      obufS[head * HD + 0] = a0 * inv; obufS[head * HD + 1] = a1 * inv;
      obufS[head * HD + 2] = a2 * inv; obufS[head * HD + 3] = a3 * inv;
      obufS[head * HD + 4] = a4 * inv; obufS[head * HD + 5] = a5 * inv;
      obufS[head * HD + 6] = a6 * inv; obufS[head * HD + 7] = a7 * inv;
    }
  }
  __syncthreads();
  // ---- proj + residual ----
  {
    int half = t >> 7, c = t & 127;
    const float* wp = p.wo + (size_t)l * D * D + c;
    float acc = 0.f;
    int d0 = half * 64;
#pragma unroll 8
    for (int d = d0; d < d0 + 64; ++d) acc += obufS[d] * wp[d * D];
    padS[half * 128 + c] = acc;
  }
  __syncthreads();
  if (t < D) {
    float hv = hrowS[t] + padS[t] + padS[128 + t] + p.bo[l * D + t];
    hrowS[t] = hv;
    p.h[row * D + t] = hv;
  }
  __syncthreads();
  lnorm(p.ln2_s + l * D, p.ln2_b + l * D, hrowS, xS, redS);
  // ---- FF1 + gelu ----
  {
    const float* w1p = p.w1 + (size_t)l * D * 512;
    float acc0 = 0.f, acc1 = 0.f;
#pragma unroll 16
    for (int d = 0; d < D; ++d) {
      float xv = xS[d];
      acc0 += xv * w1p[d * 512 + t];
      acc1 += xv * w1p[d * 512 + t + 256];
    }
    fS[t]       = geluf(acc0 + p.b1[l * 512 + t]);
    fS[t + 256] = geluf(acc1 + p.b1[l * 512 + t + 256]);
  }
  __syncthreads();
  // ---- FF2 + residual ----
  {
    int half = t >> 7, c = t & 127;
    const float* w2p = p.w2 + (size_t)l * 512 * D + c;
    float acc = 0.f;
    int d0 = half * 256;
#pragma unroll 8
    for (int d = d0; d < d0 + 256; ++d) acc += fS[d] * w2p[d * D];
    padS[half * 128 + c] = acc;
  }
  __syncthreads();
  if (t < D) {
    float hv = hrowS[t] + padS[t] + padS[128 + t] + p.b2[l * D + t];
    hrowS[t] = hv;
    p.h[row * D + t] = hv;
  }
  __syncthreads();
  if (l < NLAYER - 1) {
    lnorm(p.ln1_s + (l + 1) * D, p.ln1_b + (l + 1) * D, hrowS, xS, redS);
    qkvRow<HEAL>(p.wqkv + (size_t)(l + 1) * D * 384, p.bqkv + (l + 1) * 384, row,
                 p.qbuf, p.kc + (size_t)(l + 1) * L * D, p.vc + (size_t)(l + 1) * L * D, xS);
  } else {
    lnorm(p.lnf_s, p.lnf_b, hrowS, xS, redS);
    if (t < V * 8) {
      int col = t >> 3, seg = t & 7;
      float acc = 0.f;
      int d0 = seg * 16;
#pragma unroll
      for (int d = d0; d < d0 + 16; ++d) acc += xS[d] * p.hw[d * V + col];
      padS[t] = acc;
    }
    __syncthreads();
    if (t < V) {
      float a = padS[t*8] + padS[t*8+1] + padS[t*8+2] + padS[t*8+3]
              + padS[t*8+4] + padS[t*8+5] + padS[t*8+6] + padS[t*8+7];
      stUf(&p.logits[row * V + t], a + p.hb[t]);  // logits: always uncached
    }
    __syncthreads();
  }
}

// ---- init: lat + barrier counter, written UNCACHED (coherence point) ----
__global__ void kInit(const int* __restrict__ tokens, int* __restrict__ lat,
                      int* __restrict__ barc) {
  int i = blockIdx.x * blockDim.x + threadIdx.x;
  if (i == 0) stUi(lat, BOSX);
  if (i < L) stUi(lat + i + 1, tokens[i]);
  if (i < 64) stUi(barc + i, 0);
}

__global__ void kMega(P p) {
  __shared__ float hrowS[D];
  __shared__ float xS[D];
  __shared__ float obufS[D];
  __shared__ float fS[512];
  __shared__ float padS[256];
  __shared__ float redS[8];
  __shared__ float sortS[L];
  __shared__ int cntS[257];
  int wg = blockIdx.x, t = threadIdx.x;
  int gid = wg * 256 + t;
  int* cnt = p.barc;
  int b = 0;

  // ---- phase A: full pass (cached K/V + full-fence barriers) ----
  for (int row = wg; row < L; row += NWG) rowPre<false>(row, p, hrowS, xS, redS);
  barFull(cnt, b);
  for (int l = 0; l < NLAYER; ++l) {
    for (int row = wg; row < L; row += NWG)
      rowMain<false>(row, l, 0, p, hrowS, xS, obufS, fS, padS, redS);
    barFull(cnt, b);
  }

  // ---- log-likelihoods (logits read uncached) ----
  if (gid < L) {
    float r[V];
#pragma unroll
    for (int v = 0; v < V; ++v) r[v] = ldUf(&p.logits[gid * V + v]);
    float m = r[0];
#pragma unroll
    for (int v = 1; v < V; ++v) m = fmaxf(m, r[v]);
    float s = 0.f;
#pragma unroll
    for (int v = 0; v < V; ++v) s += expf(r[v] - m);
    int tok = ldUi(&p.lat[gid + 1]);
    p.ll_[gid] = r[tok] - (m + logf(s));
  }
  barFull(cnt, b);

  // ---- sort + quantile + heal list + bounds + heal 0 (WG 0) ----
  if (wg == 0) {
    for (int i = t; i < L; i += 256) sortS[i] = p.ll_[i];
    __syncthreads();
    for (int ksz = 2; ksz <= L; ksz <<= 1) {
      for (int j = ksz >> 1; j; j >>= 1) {
        for (int i = t; i < L; i += 256) {
          int l2 = i ^ j;
          if (l2 > i) {
            bool up = ((i & ksz) == 0);
            float a = sortS[i], bb = sortS[l2];
            if ((a > bb) == up) { sortS[i] = bb; sortS[l2] = a; }
          }
        }
        __syncthreads();
      }
    }
    if (t == 0) {
      double frac = 0.03 * 1023.0 - 30.0;  // 0.69
      redS[0] = (float)((double)sortS[30] + frac * ((double)sortS[31] - (double)sortS[30]));
    }
    __syncthreads();
    float val = redS[0];
    float lv[4];
    int loc[4], cc = 0;
#pragma unroll
    for (int j = 0; j < 4; ++j) lv[j] = p.ll_[t * 4 + j];
#pragma unroll
    for (int j = 0; j < 4; ++j)
      if (lv[j] < val) loc[cc++] = t * 4 + j;
    cntS[t] = cc;
    __syncthreads();
    if (t == 0) {
      int run = 0;
      for (int i = 0; i < 256; ++i) { int c = cntS[i]; cntS[i] = run; run += c; }
      cntS[256] = run;
    }
    __syncthreads();
    int base = cntS[t];
    for (int j = 0; j < cc; ++j)
      if (base + j < NHEAL) p.heal_row[base + j] = loc[j];
    __syncthreads();
    if (t == 0) {
      int c = cntS[256];
      if (c > NHEAL) c = NHEAL;
      for (int k = 0; k < NHEAL; ++k) {
        if (k < c) {
          p.bounds[2 * k] = (k == 0) ? 1 : (p.heal_row[k - 1] + 1);
          p.bounds[2 * k + 1] = (k == 0) ? 0 : p.heal_row[k];
        } else {
          p.heal_row[k] = -1;
          p.bounds[2 * k] = 1;
          p.bounds[2 * k + 1] = 0;
        }
      }
      p.bounds[2 * NHEAL] = (c > 0) ? (p.heal_row[c - 1] + 1) : L;
      p.bounds[2 * NHEAL + 1] = L - 1;
      if (c > 0) {
        int r = p.heal_row[0];
        int best = 0; float bv = ldUf(&p.logits[r * V]);
        for (int v = 1; v < BOSX; ++v) {
          float x = ldUf(&p.logits[r * V + v]);
          if (x > bv) { bv = x; best = v; }
        }
        stUi(&p.lat[r + 1], best);
      }
    }
  }
  barFull(cnt, b);  // publishes heal_row/bounds (cached) + drains lat store

  int split = p.heal_row[0] + 1;  // first recomputed row; rows < split stay cached

  // ---- chunks 1..30 (heal) and NHEAL (tail): fence-free barriers ----
  for (int k = 1; k <= NHEAL; ++k) {
    int cs = p.bounds[2 * k], ce = p.bounds[2 * k + 1];
    if (cs <= ce) {
      for (int row = cs + wg; row <= ce; row += NWG) rowPre<true>(row, p, hrowS, xS, redS);
      barLight(cnt, b);
      for (int l = 0; l < NLAYER; ++l) {
        for (int row = cs + wg; row <= ce; row += NWG)
          rowMain<true>(row, l, split, p, hrowS, xS, obufS, fS, padS, redS);
        barLight(cnt, b);
      }
      if (k < NHEAL && wg == 0 && t == 0) {
        int r = p.heal_row[k];
        if (r >= 0) {
          int best = 0; float bv = ldUf(&p.logits[r * V]);
          for (int v = 1; v < BOSX; ++v) {
            float x = ldUf(&p.logits[r * V + v]);
            if (x > bv) { bv = x; best = v; }
          }
          stUi(&p.lat[r + 1], best);
        }
      }
      barLight(cnt, b);
    }
  }

  // ---- tokens out ----
  if (gid < L) p.out_tok[gid] = (float)ldUi(&p.lat[gid + 1]);
}

extern "C" void kernel_launch(void* const* d_in, const int* in_sizes, int n_in,
                              void* d_out, int out_size, void* d_ws, size_t ws_size,
                              hipStream_t stream) {
  P prm;
  prm.tokens = (const int*)d_in[0];
  prm.emb    = (const float*)d_in[1];
  prm.pos    = (const float*)d_in[2];
  prm.ln1_s  = (const float*)d_in[3];
  prm.ln1_b  = (const float*)d_in[4];
  prm.wqkv   = (const float*)d_in[5];
  prm.bqkv   = (const float*)d_in[6];
  prm.wo     = (const float*)d_in[7];
  prm.bo     = (const float*)d_in[8];
  prm.ln2_s  = (const float*)d_in[9];
  prm.ln2_b  = (const float*)d_in[10];
  prm.w1     = (const float*)d_in[11];
  prm.b1     = (const float*)d_in[12];
  prm.w2     = (const float*)d_in[13];
  prm.b2     = (const float*)d_in[14];
  prm.lnf_s  = (const float*)d_in[15];
  prm.lnf_b  = (const float*)d_in[16];
  prm.hw     = (const float*)d_in[17];
  prm.hb     = (const float*)d_in[18];

  float* ws = (float*)d_ws;
  prm.h    = ws;                       // L*D
  prm.qbuf = prm.h + L * D;            // L*D
  prm.kc   = prm.qbuf + L * D;         // NLAYER*L*D
  prm.vc   = prm.kc + NLAYER * L * D;  // NLAYER*L*D
  prm.ll_  = prm.vc + NLAYER * L * D;  // L
  prm.lat      = (int*)(prm.ll_ + L);  // 1025 (pad 1032)
  prm.heal_row = prm.lat + 1032;       // 32
  prm.bounds   = prm.heal_row + 32;    // 64
  prm.barc     = prm.bounds + 64;      // 64

  prm.logits  = (float*)d_out;         // L*V
  prm.out_tok = prm.logits + L * V;    // L

  kInit<<<5, 256, 0, stream>>>(prm.tokens, prm.lat, prm.barc);

  void* args[] = { &prm };
  (void)hipLaunchCooperativeKernel((const void*)kMega, dim3(NWG), dim3(256), args, 0, stream);
}

// Round 7
// 31585.165 us; speedup vs baseline: 7.6546x; 2.9365x over previous
//
#include <hip/hip_runtime.h>
#include <math.h>

#define D 128
#define NLAYER 16
#define V 17
#define L 1024
#define BOSX 16
#define NWG 256
#define NT 512

struct P {
  const int* tokens;
  const float *emb, *pos, *ln1_s, *ln1_b, *wqkv, *bqkv, *wo, *bo;
  const float *ln2_s, *ln2_b, *w1, *b1, *w2, *b2, *lnf_s, *lnf_b, *hw, *hb;
  float *kc, *vc, *ll_;
  int *lat, *heal_row, *barc, *done, *heals_done;
  float *logits, *out_tok;
};

// ---- uncached (coherence-point) accessors ----
__device__ __forceinline__ float ldUf(const float* p) {
  return __hip_atomic_load((float*)p, __ATOMIC_RELAXED, __HIP_MEMORY_SCOPE_SYSTEM);
}
__device__ __forceinline__ float2 ldU2(const float* p) {
  union { double d; float2 f; } u;
  u.d = __hip_atomic_load((double*)p, __ATOMIC_RELAXED, __HIP_MEMORY_SCOPE_SYSTEM);
  return u.f;
}
__device__ __forceinline__ void stUf(float* p, float v) {
  __hip_atomic_store(p, v, __ATOMIC_RELAXED, __HIP_MEMORY_SCOPE_SYSTEM);
}
__device__ __forceinline__ int ldUi(const int* p) {
  return __hip_atomic_load((int*)p, __ATOMIC_RELAXED, __HIP_MEMORY_SCOPE_SYSTEM);
}
__device__ __forceinline__ void stUi(int* p, int v) {
  __hip_atomic_store(p, v, __ATOMIC_RELAXED, __HIP_MEMORY_SCOPE_SYSTEM);
}

// ---- full barrier (phase A only): wb/inv fence, relaxed spin ----
__device__ __forceinline__ void barFull(int* cnt, int& b) {
  asm volatile("s_waitcnt vmcnt(0)" ::: "memory");
  __syncthreads();
  if (threadIdx.x == 0) {
    __threadfence();
    __hip_atomic_fetch_add(cnt, 1, __ATOMIC_RELAXED, __HIP_MEMORY_SCOPE_SYSTEM);
    int tgt = (b + 1) * NWG;
    while (__hip_atomic_load(cnt, __ATOMIC_RELAXED, __HIP_MEMORY_SCOPE_SYSTEM) < tgt)
      __builtin_amdgcn_s_sleep(8);
    __threadfence();
  }
  b += 1;
  __syncthreads();
}

__device__ __forceinline__ float geluf(float a) {
  float cgv = 0.7978845608028654f * (a + 0.044715f * a * a * a);
  cgv = fminf(fmaxf(cgv, -15.f), 15.f);
  float e = __expf(2.f * cgv);
  return 0.5f * a * (1.f + (e - 1.f) / (e + 1.f));
}

// LayerNorm in[0..127]->out[0..127], 512 threads, trailing sync
__device__ void lnorm(const float* __restrict__ s, const float* __restrict__ b,
                      const float* in, float* out, float* red) {
  int t = threadIdx.x;
  float v = (t < D) ? in[t] : 0.f;
  float sm = v;
#pragma unroll
  for (int o = 32; o; o >>= 1) sm += __shfl_xor(sm, o, 64);
  if ((t & 63) == 0) red[t >> 6] = sm;
  __syncthreads();
  float mean = (red[0]+red[1]+red[2]+red[3]+red[4]+red[5]+red[6]+red[7]) * (1.f/128.f);
  float d = (t < D) ? (v - mean) : 0.f;
  float vs = d * d;
#pragma unroll
  for (int o = 32; o; o >>= 1) vs += __shfl_xor(vs, o, 64);
  if ((t & 63) == 0) red[8 + (t >> 6)] = vs;
  __syncthreads();
  float rstd = rsqrtf((red[8]+red[9]+red[10]+red[11]+red[12]+red[13]+red[14]+red[15]) * (1.f/128.f) + 1e-5f);
  if (t < D) out[t] = d * rstd * s[t] + b[t];
  __syncthreads();
}

// QKV for one row: q->LDS, K/V->global (uncached + done-chain when HEAL)
template <bool HEAL>
__device__ void qkvPub(const P& p, int l, int row, int split, const float* x, float* qrow) {
  int t = threadIdx.x;
  if (t < 384) {
    const float* w = p.wqkv + (size_t)l * D * 384 + t;
    float a = 0.f;
#pragma unroll 8
    for (int d = 0; d < D; ++d) a += x[d] * w[d * 384];
    a += p.bqkv[l * 384 + t];
    float* kcl = p.kc + (size_t)l * L * D + (size_t)row * D;
    float* vcl = p.vc + (size_t)l * L * D + (size_t)row * D;
    if (t < D) qrow[t] = a;
    else if (t < 256) { if (HEAL) stUf(&kcl[t - 128], a); else kcl[t - 128] = a; }
    else              { if (HEAL) stUf(&vcl[t - 256], a); else vcl[t - 256] = a; }
  }
  if (HEAL) {
    asm volatile("s_waitcnt vmcnt(0)" ::: "memory");
    __syncthreads();
    if (threadIdx.x == 0) {
      int* dl = p.done + l * L;
      if (row - 1 >= split)
        while (ldUi(&dl[row - 1]) < 1) __builtin_amdgcn_s_sleep(2);
      stUi(&dl[row], 1);
    }
    __syncthreads();
  } else {
    __syncthreads();
  }
}

// attention(l)+proj+res+LN2+FF1+FF2+res for one row (h in LDS)
template <bool HEAL>
__device__ void attnProjFFN(const P& p, int row, int l, int split,
                            float* hrow, const float* qrow,
                            float* oS, float* xnS, float* fS, float* padS, float* redS) {
  int t = threadIdx.x;
  const float* kcl = p.kc + (size_t)l * L * D;
  const float* vcl = p.vc + (size_t)l * L * D;
  int head = t >> 5, lane = t & 31;
  const float* qh = qrow + head * 8;
  float q0=qh[0],q1=qh[1],q2=qh[2],q3=qh[3],q4=qh[4],q5=qh[5],q6=qh[6],q7=qh[7];
  float sum = 0.f, a0=0,a1=0,a2=0,a3=0,a4=0,a5=0,a6=0,a7=0;
  int capC = HEAL ? split : (row + 1);  // cached segment bound
#pragma unroll 2
  for (int key = lane; key < capC; key += 32) {
    const float4* kp = (const float4*)(kcl + (size_t)key * D + head * 8);
    float4 k0 = kp[0], k1 = kp[1];
    float sc = q0*k0.x+q1*k0.y+q2*k0.z+q3*k0.w+q4*k1.x+q5*k1.y+q6*k1.z+q7*k1.w;
    float pr = __expf(sc * 0.35355339059327376f);
    const float4* vp = (const float4*)(vcl + (size_t)key * D + head * 8);
    float4 v0 = vp[0], v1 = vp[1];
    sum += pr;
    a0+=pr*v0.x; a1+=pr*v0.y; a2+=pr*v0.z; a3+=pr*v0.w;
    a4+=pr*v1.x; a5+=pr*v1.y; a6+=pr*v1.z; a7+=pr*v1.w;
  }
  if (HEAL) {
    // uncached segment: rows >= split (rewritten during healing)
#pragma unroll 2
    for (int key = split + ((lane - split) & 31); key <= row; key += 32) {
      const float* kp = kcl + (size_t)key * D + head * 8;
      float2 ka=ldU2(kp), kb=ldU2(kp+2), kc2=ldU2(kp+4), kd=ldU2(kp+6);
      float sc = q0*ka.x+q1*ka.y+q2*kb.x+q3*kb.y+q4*kc2.x+q5*kc2.y+q6*kd.x+q7*kd.y;
      float pr = __expf(sc * 0.35355339059327376f);
      const float* vp = vcl + (size_t)key * D + head * 8;
      float2 va=ldU2(vp), vb=ldU2(vp+2), vc2=ldU2(vp+4), vd=ldU2(vp+6);
      sum += pr;
      a0+=pr*va.x; a1+=pr*va.y; a2+=pr*vb.x; a3+=pr*vb.y;
      a4+=pr*vc2.x; a5+=pr*vc2.y; a6+=pr*vd.x; a7+=pr*vd.y;
    }
  }
#pragma unroll
  for (int o = 1; o < 32; o <<= 1) {
    sum += __shfl_xor(sum, o, 32);
    a0 += __shfl_xor(a0, o, 32); a1 += __shfl_xor(a1, o, 32);
    a2 += __shfl_xor(a2, o, 32); a3 += __shfl_xor(a3, o, 32);
    a4 += __shfl_xor(a4, o, 32); a5 += __shfl_xor(a5, o, 32);
    a6 += __shfl_xor(a6, o, 32); a7 += __shfl_xor(a7, o, 32);
  }
  if (lane == 0) {
    float inv = 1.f / sum;
    oS[head*8+0]=a0*inv; oS[head*8+1]=a1*inv; oS[head*8+2]=a2*inv; oS[head*8+3]=a3*inv;
    oS[head*8+4]=a4*inv; oS[head*8+5]=a5*inv; oS[head*8+6]=a6*inv; oS[head*8+7]=a7*inv;
  }
  __syncthreads();
  // ---- proj: 4 segs x 32 deep ----
  {
    int col = t & 127, seg = t >> 7;
    const float* wp = p.wo + (size_t)l * D * D + col;
    float acc = 0.f;
    int d0 = seg * 32;
#pragma unroll 8
    for (int d = d0; d < d0 + 32; ++d) acc += oS[d] * wp[d * D];
    padS[t] = acc;
  }
  __syncthreads();
  if (t < D) hrow[t] += padS[t] + padS[t+128] + padS[t+256] + padS[t+384] + p.bo[l * D + t];
  __syncthreads();
  lnorm(p.ln2_s + l * D, p.ln2_b + l * D, hrow, xnS, redS);
  // ---- FF1: col per thread ----
  {
    const float* w1p = p.w1 + (size_t)l * D * 512 + t;
    float acc = 0.f;
#pragma unroll 8
    for (int d = 0; d < D; ++d) acc += xnS[d] * w1p[d * 512];
    fS[t] = geluf(acc + p.b1[l * 512 + t]);
  }
  __syncthreads();
  // ---- FF2: 4 segs x 128 deep ----
  {
    int col = t & 127, seg = t >> 7;
    const float* w2p = p.w2 + (size_t)l * 512 * D + col;
    float acc = 0.f;
    int d0 = seg * 128;
#pragma unroll 8
    for (int d = d0; d < d0 + 128; ++d) acc += fS[d] * w2p[d * D];
    padS[t] = acc;
  }
  __syncthreads();
  if (t < D) hrow[t] += padS[t] + padS[t+128] + padS[t+256] + padS[t+384] + p.b2[l * D + t];
  __syncthreads();
}

// LNf + head for one row; logits -> global (+ oS LDS for argmax)
template <bool HEAL>
__device__ void headRow(const P& p, int row, float* hrow,
                        float* xnS, float* redS, float* padS, float* oS) {
  lnorm(p.lnf_s, p.lnf_b, hrow, xnS, redS);
  int t = threadIdx.x;
  if (t < V * 8) {
    int col = t >> 3, seg = t & 7;
    float acc = 0.f;
    int d0 = seg * 16;
#pragma unroll
    for (int d = d0; d < d0 + 16; ++d) acc += xnS[d] * p.hw[d * V + col];
    padS[t] = acc;
  }
  __syncthreads();
  if (t < V) {
    float a = padS[t*8]+padS[t*8+1]+padS[t*8+2]+padS[t*8+3]
            + padS[t*8+4]+padS[t*8+5]+padS[t*8+6]+padS[t*8+7] + p.hb[t];
    oS[t] = a;
    if (HEAL) stUf(&p.logits[row * V + t], a);
    else      p.logits[row * V + t] = a;
  }
  __syncthreads();
}

// ---- init: lat + flags, all uncached ----
__global__ void kInit(const int* __restrict__ tokens, int* __restrict__ lat,
                      int* __restrict__ barc, int* __restrict__ done,
                      int* __restrict__ hd) {
  int i = blockIdx.x * blockDim.x + threadIdx.x;
  if (i == 0) stUi(lat, BOSX);
  if (i < L) stUi(lat + i + 1, tokens[i]);
  if (i < 64) stUi(barc + i, 0);
  if (i < 16) stUi(hd + i, 0);
  if (i < NLAYER * L) stUi(done + i, 0);
}

__global__ void __launch_bounds__(NT, 1) kMega(P p) {
  __shared__ float hS[4][D];
  __shared__ float qS[4][D];
  __shared__ float xnS[D];
  __shared__ float oS[D];
  __shared__ float fS[512];
  __shared__ float padS[512];
  __shared__ float redS[16];
  __shared__ float sortS[L];
  __shared__ int cntS[NT + 1];
  int wg = blockIdx.x, t = threadIdx.x;
  int b = 0;
  int* cnt = p.barc;

  // ================= PHASE A: full pass, 4 rows/WG, cached =================
  for (int i = 0; i < 4; ++i) {
    int row = wg + i * NWG;
    int tok = p.lat[row];
    if (t < D) hS[i][t] = p.emb[tok * D + t] + p.pos[row * D + t];
    __syncthreads();
    lnorm(p.ln1_s, p.ln1_b, hS[i], xnS, redS);
    qkvPub<false>(p, 0, row, 0, xnS, qS[i]);
  }
  barFull(cnt, b);
  for (int l = 0; l < NLAYER; ++l) {
    for (int i = 0; i < 4; ++i) {
      int row = wg + i * NWG;
      attnProjFFN<false>(p, row, l, 0, hS[i], qS[i], oS, xnS, fS, padS, redS);
      if (l < NLAYER - 1) {
        lnorm(p.ln1_s + (l+1)*D, p.ln1_b + (l+1)*D, hS[i], xnS, redS);
        qkvPub<false>(p, l + 1, row, 0, xnS, qS[i]);
      } else {
        headRow<false>(p, row, hS[i], xnS, redS, padS, oS);
      }
    }
    barFull(cnt, b);
  }

  // ================= log-likelihoods =================
  {
    int gid = wg * NT + t;
    if (gid < L) {
      float r[V];
#pragma unroll
      for (int v = 0; v < V; ++v) r[v] = p.logits[gid * V + v];
      float m = r[0];
#pragma unroll
      for (int v = 1; v < V; ++v) m = fmaxf(m, r[v]);
      float s = 0.f;
#pragma unroll
      for (int v = 0; v < V; ++v) s += expf(r[v] - m);
      p.ll_[gid] = r[p.lat[gid + 1]] - (m + logf(s));
    }
  }
  barFull(cnt, b);

  // ================= sort + quantile + heal list (WG 0) =================
  if (wg == 0) {
    for (int i = t; i < L; i += NT) sortS[i] = p.ll_[i];
    __syncthreads();
    for (int ksz = 2; ksz <= L; ksz <<= 1) {
      for (int j = ksz >> 1; j; j >>= 1) {
        for (int i = t; i < L; i += NT) {
          int l2 = i ^ j;
          if (l2 > i) {
            bool up = ((i & ksz) == 0);
            float a = sortS[i], bb = sortS[l2];
            if ((a > bb) == up) { sortS[i] = bb; sortS[l2] = a; }
          }
        }
        __syncthreads();
      }
    }
    if (t == 0) {
      double frac = 0.03 * 1023.0 - 30.0;  // 0.69
      redS[0] = (float)((double)sortS[30] + frac * ((double)sortS[31] - (double)sortS[30]));
    }
    __syncthreads();
    float val = redS[0];
    float lv0 = p.ll_[t * 2], lv1 = p.ll_[t * 2 + 1];
    int loc[2], cc = 0;
    if (lv0 < val) loc[cc++] = t * 2;
    if (lv1 < val) loc[cc++] = t * 2 + 1;
    cntS[t] = cc;
    __syncthreads();
    if (t == 0) {
      int run = 0;
      for (int i = 0; i < NT; ++i) { int c2 = cntS[i]; cntS[i] = run; run += c2; }
      cntS[NT] = run;
    }
    __syncthreads();
    int base = cntS[t];
    for (int j = 0; j < cc; ++j)
      if (base + j < 31) p.heal_row[base + j] = loc[j];
    __syncthreads();
    if (t == 0) {
      int c = cntS[NT]; if (c > 31) c = 31;
      p.heal_row[31] = c;
      stUi(p.heals_done, 1);
      if (c > 0) {
        int r0 = p.heal_row[0];
        int best = 0; float bv = p.logits[r0 * V];
        for (int v = 1; v < BOSX; ++v) {
          float x = p.logits[r0 * V + v];
          if (x > bv) { bv = x; best = v; }
        }
        stUi(&p.lat[r0 + 1], best);
      }
    }
  }
  barFull(cnt, b);

  // ================= HEAL: barrier-free row pipeline =================
  int c = p.heal_row[31];
  int split = (c > 0) ? (p.heal_row[0] + 1) : L;
  for (int r = split + wg; r < L; r += NWG) {
    int nh = 0, hk = -1;
    for (int j = 0; j < c; ++j) {
      nh += (p.heal_row[j] < r) ? 1 : 0;
      if (j >= 1 && p.heal_row[j] == r) hk = j;
    }
    if (t == 0) {
      while (ldUi(p.heals_done) < nh) __builtin_amdgcn_s_sleep(2);
      cntS[0] = ldUi(&p.lat[r]);
    }
    __syncthreads();
    int tok = cntS[0];
    if (t < D) hS[0][t] = p.emb[tok * D + t] + p.pos[r * D + t];
    __syncthreads();
    lnorm(p.ln1_s, p.ln1_b, hS[0], xnS, redS);
    qkvPub<true>(p, 0, r, split, xnS, qS[0]);
    for (int l = 0; l < NLAYER; ++l) {
      attnProjFFN<true>(p, r, l, split, hS[0], qS[0], oS, xnS, fS, padS, redS);
      if (l < NLAYER - 1) {
        lnorm(p.ln1_s + (l+1)*D, p.ln1_b + (l+1)*D, hS[0], xnS, redS);
        qkvPub<true>(p, l + 1, r, split, xnS, qS[0]);
      } else {
        headRow<true>(p, r, hS[0], xnS, redS, padS, oS);
      }
    }
    if (hk >= 0 && t == 0) {
      int best = 0; float bv = oS[0];
      for (int v = 1; v < BOSX; ++v)
        if (oS[v] > bv) { bv = oS[v]; best = v; }
      stUi(&p.lat[r + 1], best);
      asm volatile("s_waitcnt vmcnt(0)" ::: "memory");
      stUi(p.heals_done, hk + 1);
    }
  }

  barFull(cnt, b);

  // ================= tokens out =================
  {
    int gid = wg * NT + t;
    if (gid < L) p.out_tok[gid] = (float)ldUi(&p.lat[gid + 1]);
  }
}

extern "C" void kernel_launch(void* const* d_in, const int* in_sizes, int n_in,
                              void* d_out, int out_size, void* d_ws, size_t ws_size,
                              hipStream_t stream) {
  P prm;
  prm.tokens = (const int*)d_in[0];
  prm.emb    = (const float*)d_in[1];
  prm.pos    = (const float*)d_in[2];
  prm.ln1_s  = (const float*)d_in[3];
  prm.ln1_b  = (const float*)d_in[4];
  prm.wqkv   = (const float*)d_in[5];
  prm.bqkv   = (const float*)d_in[6];
  prm.wo     = (const float*)d_in[7];
  prm.bo     = (const float*)d_in[8];
  prm.ln2_s  = (const float*)d_in[9];
  prm.ln2_b  = (const float*)d_in[10];
  prm.w1     = (const float*)d_in[11];
  prm.b1     = (const float*)d_in[12];
  prm.w2     = (const float*)d_in[13];
  prm.b2     = (const float*)d_in[14];
  prm.lnf_s  = (const float*)d_in[15];
  prm.lnf_b  = (const float*)d_in[16];
  prm.hw     = (const float*)d_in[17];
  prm.hb     = (const float*)d_in[18];

  float* ws = (float*)d_ws;
  prm.kc   = ws;                            // NLAYER*L*D
  prm.vc   = prm.kc + (size_t)NLAYER*L*D;   // NLAYER*L*D
  prm.ll_  = prm.vc + (size_t)NLAYER*L*D;   // L
  prm.lat        = (int*)(prm.ll_ + L);     // 1025 (pad 1032)
  prm.heal_row   = prm.lat + 1032;          // 32 ([31] = count)
  prm.barc       = prm.heal_row + 32;       // 64
  prm.done       = prm.barc + 64;           // NLAYER*L
  prm.heals_done = prm.done + NLAYER * L;   // 16

  prm.logits  = (float*)d_out;              // L*V
  prm.out_tok = prm.logits + L * V;         // L

  kInit<<<64, 256, 0, stream>>>(prm.tokens, prm.lat, prm.barc, prm.done, prm.heals_done);

  void* args[] = { &prm };
  (void)hipLaunchCooperativeKernel((const void*)kMega, dim3(NWG), dim3(NT), args, 0, stream);
}

// Round 8
// 21626.750 us; speedup vs baseline: 11.1792x; 1.4605x over previous
//
#include <hip/hip_runtime.h>
#include <math.h>

#define D 128
#define NLAYER 16
#define V 17
#define L 1024
#define BOSX 16
#define NWG 256
#define NT 512

struct P {
  const int* tokens;
  const float *emb, *pos, *ln1_s, *ln1_b, *wqkv, *bqkv, *wo, *bo;
  const float *ln2_s, *ln2_b, *w1, *b1, *w2, *b2, *lnf_s, *lnf_b, *hw, *hb;
  float *kc, *vc, *ll_;
  int *lat, *heal_row, *barc, *done, *heals_done;
  float *logits, *out_tok;
};

// ---- uncached (coherence-point) accessors ----
__device__ __forceinline__ void stUf(float* p, float v) {
  __hip_atomic_store(p, v, __ATOMIC_RELAXED, __HIP_MEMORY_SCOPE_SYSTEM);
}
__device__ __forceinline__ int ldUi(const int* p) {
  return __hip_atomic_load((int*)p, __ATOMIC_RELAXED, __HIP_MEMORY_SCOPE_SYSTEM);
}
__device__ __forceinline__ void stUi(int* p, int v) {
  __hip_atomic_store(p, v, __ATOMIC_RELAXED, __HIP_MEMORY_SCOPE_SYSTEM);
}

// ---- full barrier (phase A + transitions): wb/inv fence, relaxed spin ----
__device__ __forceinline__ void barFull(int* cnt, int& b) {
  asm volatile("s_waitcnt vmcnt(0)" ::: "memory");
  __syncthreads();
  if (threadIdx.x == 0) {
    __threadfence();
    __hip_atomic_fetch_add(cnt, 1, __ATOMIC_RELAXED, __HIP_MEMORY_SCOPE_AGENT);
    int tgt = (b + 1) * NWG;
    while (__hip_atomic_load(cnt, __ATOMIC_RELAXED, __HIP_MEMORY_SCOPE_AGENT) < tgt)
      __builtin_amdgcn_s_sleep(8);
    __threadfence();
  }
  b += 1;
  __syncthreads();
}

__device__ __forceinline__ float geluf(float a) {
  float cgv = 0.7978845608028654f * (a + 0.044715f * a * a * a);
  cgv = fminf(fmaxf(cgv, -15.f), 15.f);
  float e = __expf(2.f * cgv);
  return 0.5f * a * (1.f + (e - 1.f) / (e + 1.f));
}

// LayerNorm in[0..127]->out[0..127], 512 threads, trailing sync
__device__ void lnorm(const float* __restrict__ s, const float* __restrict__ b,
                      const float* in, float* out, float* red) {
  int t = threadIdx.x;
  float v = (t < D) ? in[t] : 0.f;
  float sm = v;
#pragma unroll
  for (int o = 32; o; o >>= 1) sm += __shfl_xor(sm, o, 64);
  if ((t & 63) == 0) red[t >> 6] = sm;
  __syncthreads();
  float mean = (red[0]+red[1]+red[2]+red[3]+red[4]+red[5]+red[6]+red[7]) * (1.f/128.f);
  float d = (t < D) ? (v - mean) : 0.f;
  float vs = d * d;
#pragma unroll
  for (int o = 32; o; o >>= 1) vs += __shfl_xor(vs, o, 64);
  if ((t & 63) == 0) red[8 + (t >> 6)] = vs;
  __syncthreads();
  float rstd = rsqrtf((red[8]+red[9]+red[10]+red[11]+red[12]+red[13]+red[14]+red[15]) * (1.f/128.f) + 1e-5f);
  if (t < D) out[t] = d * rstd * s[t] + b[t];
  __syncthreads();
}

// QKV for one row: q->LDS, K/V->global.
// HEAL: K/V stores uncached (visible at coherence point, no L2 flush) + done-chain.
template <bool HEAL>
__device__ void qkvPub(const P& p, int l, int row, int split, const float* x, float* qrow) {
  int t = threadIdx.x;
  if (t < 384) {
    const float* w = p.wqkv + (size_t)l * D * 384 + t;
    float a = 0.f;
#pragma unroll 8
    for (int d = 0; d < D; ++d) a += x[d] * w[d * 384];
    a += p.bqkv[l * 384 + t];
    float* kcl = p.kc + (size_t)l * L * D + (size_t)row * D;
    float* vcl = p.vc + (size_t)l * L * D + (size_t)row * D;
    if (t < D) qrow[t] = a;
    else if (t < 256) { if (HEAL) stUf(&kcl[t - 128], a); else kcl[t - 128] = a; }
    else              { if (HEAL) stUf(&vcl[t - 256], a); else vcl[t - 256] = a; }
  }
  if (HEAL) {
    asm volatile("s_waitcnt vmcnt(0)" ::: "memory");  // uncached stores landed
    __syncthreads();
    if (threadIdx.x == 0) {
      int* dl = p.done + l * L;
      if (row - 1 >= split)
        while (ldUi(&dl[row - 1]) < 1) __builtin_amdgcn_s_sleep(1);
      stUi(&dl[row], 1);
    }
    __syncthreads();
  } else {
    __syncthreads();
  }
}

// attention(l)+proj+res+LN2+FF1+FF2+res for one row (h in LDS).
// All K/V reads CACHED: phase-A lines were invalidated by the barFull fences
// before the heal phase; heal-phase lines are demand-fetched only after their
// publish flag was observed (uncached write -> L3 -> clean cached read).
__device__ void attnProjFFN(const P& p, int row, int l,
                            float* hrow, const float* qrow,
                            float* oS, float* xnS, float* fS, float* padS, float* redS) {
  int t = threadIdx.x;
  const float* kcl = p.kc + (size_t)l * L * D;
  const float* vcl = p.vc + (size_t)l * L * D;
  int head = t >> 5, lane = t & 31;
  const float* qh = qrow + head * 8;
  float q0=qh[0],q1=qh[1],q2=qh[2],q3=qh[3],q4=qh[4],q5=qh[5],q6=qh[6],q7=qh[7];
  float sum = 0.f, a0=0,a1=0,a2=0,a3=0,a4=0,a5=0,a6=0,a7=0;
#pragma unroll 2
  for (int key = lane; key <= row; key += 32) {
    const float4* kp = (const float4*)(kcl + (size_t)key * D + head * 8);
    float4 k0 = kp[0], k1 = kp[1];
    float sc = q0*k0.x+q1*k0.y+q2*k0.z+q3*k0.w+q4*k1.x+q5*k1.y+q6*k1.z+q7*k1.w;
    float pr = __expf(sc * 0.35355339059327376f);
    const float4* vp = (const float4*)(vcl + (size_t)key * D + head * 8);
    float4 v0 = vp[0], v1 = vp[1];
    sum += pr;
    a0+=pr*v0.x; a1+=pr*v0.y; a2+=pr*v0.z; a3+=pr*v0.w;
    a4+=pr*v1.x; a5+=pr*v1.y; a6+=pr*v1.z; a7+=pr*v1.w;
  }
#pragma unroll
  for (int o = 1; o < 32; o <<= 1) {
    sum += __shfl_xor(sum, o, 32);
    a0 += __shfl_xor(a0, o, 32); a1 += __shfl_xor(a1, o, 32);
    a2 += __shfl_xor(a2, o, 32); a3 += __shfl_xor(a3, o, 32);
    a4 += __shfl_xor(a4, o, 32); a5 += __shfl_xor(a5, o, 32);
    a6 += __shfl_xor(a6, o, 32); a7 += __shfl_xor(a7, o, 32);
  }
  if (lane == 0) {
    float inv = 1.f / sum;
    oS[head*8+0]=a0*inv; oS[head*8+1]=a1*inv; oS[head*8+2]=a2*inv; oS[head*8+3]=a3*inv;
    oS[head*8+4]=a4*inv; oS[head*8+5]=a5*inv; oS[head*8+6]=a6*inv; oS[head*8+7]=a7*inv;
  }
  __syncthreads();
  // ---- proj: 4 segs x 32 deep ----
  {
    int col = t & 127, seg = t >> 7;
    const float* wp = p.wo + (size_t)l * D * D + col;
    float acc = 0.f;
    int d0 = seg * 32;
#pragma unroll 8
    for (int d = d0; d < d0 + 32; ++d) acc += oS[d] * wp[d * D];
    padS[t] = acc;
  }
  __syncthreads();
  if (t < D) hrow[t] += padS[t] + padS[t+128] + padS[t+256] + padS[t+384] + p.bo[l * D + t];
  __syncthreads();
  lnorm(p.ln2_s + l * D, p.ln2_b + l * D, hrow, xnS, redS);
  // ---- FF1: col per thread ----
  {
    const float* w1p = p.w1 + (size_t)l * D * 512 + t;
    float acc = 0.f;
#pragma unroll 8
    for (int d = 0; d < D; ++d) acc += xnS[d] * w1p[d * 512];
    fS[t] = geluf(acc + p.b1[l * 512 + t]);
  }
  __syncthreads();
  // ---- FF2: 4 segs x 128 deep ----
  {
    int col = t & 127, seg = t >> 7;
    const float* w2p = p.w2 + (size_t)l * 512 * D + col;
    float acc = 0.f;
    int d0 = seg * 128;
#pragma unroll 8
    for (int d = d0; d < d0 + 128; ++d) acc += fS[d] * w2p[d * D];
    padS[t] = acc;
  }
  __syncthreads();
  if (t < D) hrow[t] += padS[t] + padS[t+128] + padS[t+256] + padS[t+384] + p.b2[l * D + t];
  __syncthreads();
}

// LNf + head for one row; logits -> global (+ oS LDS for argmax)
template <bool HEAL>
__device__ void headRow(const P& p, int row, float* hrow,
                        float* xnS, float* redS, float* padS, float* oS) {
  lnorm(p.lnf_s, p.lnf_b, hrow, xnS, redS);
  int t = threadIdx.x;
  if (t < V * 8) {
    int col = t >> 3, seg = t & 7;
    float acc = 0.f;
    int d0 = seg * 16;
#pragma unroll
    for (int d = d0; d < d0 + 16; ++d) acc += xnS[d] * p.hw[d * V + col];
    padS[t] = acc;
  }
  __syncthreads();
  if (t < V) {
    float a = padS[t*8]+padS[t*8+1]+padS[t*8+2]+padS[t*8+3]
            + padS[t*8+4]+padS[t*8+5]+padS[t*8+6]+padS[t*8+7] + p.hb[t];
    oS[t] = a;
    if (HEAL) stUf(&p.logits[row * V + t], a);
    else      p.logits[row * V + t] = a;
  }
  __syncthreads();
}

// ---- init: lat + flags, all uncached ----
__global__ void kInit(const int* __restrict__ tokens, int* __restrict__ lat,
                      int* __restrict__ barc, int* __restrict__ done,
                      int* __restrict__ hd) {
  int i = blockIdx.x * blockDim.x + threadIdx.x;
  if (i == 0) stUi(lat, BOSX);
  if (i < L) stUi(lat + i + 1, tokens[i]);
  if (i < 64) stUi(barc + i, 0);
  if (i < 16) stUi(hd + i, 0);
  if (i < NLAYER * L) stUi(done + i, 0);
}

__global__ void __launch_bounds__(NT, 1) kMega(P p) {
  __shared__ float hS[4][D];
  __shared__ float qS[4][D];
  __shared__ float xnS[D];
  __shared__ float oS[D];
  __shared__ float fS[512];
  __shared__ float padS[512];
  __shared__ float redS[16];
  __shared__ float sortS[L];
  __shared__ int cntS[NT + 1];
  int wg = blockIdx.x, t = threadIdx.x;
  int b = 0;
  int* cnt = p.barc;

  // ================= PHASE A: full pass, 4 rows/WG, cached =================
  for (int i = 0; i < 4; ++i) {
    int row = wg + i * NWG;
    int tok = p.lat[row];
    if (t < D) hS[i][t] = p.emb[tok * D + t] + p.pos[row * D + t];
    __syncthreads();
    lnorm(p.ln1_s, p.ln1_b, hS[i], xnS, redS);
    qkvPub<false>(p, 0, row, 0, xnS, qS[i]);
  }
  barFull(cnt, b);
  for (int l = 0; l < NLAYER; ++l) {
    for (int i = 0; i < 4; ++i) {
      int row = wg + i * NWG;
      attnProjFFN(p, row, l, hS[i], qS[i], oS, xnS, fS, padS, redS);
      if (l < NLAYER - 1) {
        lnorm(p.ln1_s + (l+1)*D, p.ln1_b + (l+1)*D, hS[i], xnS, redS);
        qkvPub<false>(p, l + 1, row, 0, xnS, qS[i]);
      } else {
        headRow<false>(p, row, hS[i], xnS, redS, padS, oS);
      }
    }
    barFull(cnt, b);
  }

  // ================= log-likelihoods =================
  {
    int gid = wg * NT + t;
    if (gid < L) {
      float r[V];
#pragma unroll
      for (int v = 0; v < V; ++v) r[v] = p.logits[gid * V + v];
      float m = r[0];
#pragma unroll
      for (int v = 1; v < V; ++v) m = fmaxf(m, r[v]);
      float s = 0.f;
#pragma unroll
      for (int v = 0; v < V; ++v) s += expf(r[v] - m);
      p.ll_[gid] = r[p.lat[gid + 1]] - (m + logf(s));
    }
  }
  barFull(cnt, b);

  // ================= sort + quantile + heal list (WG 0) =================
  if (wg == 0) {
    for (int i = t; i < L; i += NT) sortS[i] = p.ll_[i];
    __syncthreads();
    for (int ksz = 2; ksz <= L; ksz <<= 1) {
      for (int j = ksz >> 1; j; j >>= 1) {
        for (int i = t; i < L; i += NT) {
          int l2 = i ^ j;
          if (l2 > i) {
            bool up = ((i & ksz) == 0);
            float a = sortS[i], bb = sortS[l2];
            if ((a > bb) == up) { sortS[i] = bb; sortS[l2] = a; }
          }
        }
        __syncthreads();
      }
    }
    if (t == 0) {
      double frac = 0.03 * 1023.0 - 30.0;  // 0.69
      redS[0] = (float)((double)sortS[30] + frac * ((double)sortS[31] - (double)sortS[30]));
    }
    __syncthreads();
    float val = redS[0];
    float lv0 = p.ll_[t * 2], lv1 = p.ll_[t * 2 + 1];
    int loc[2], cc = 0;
    if (lv0 < val) loc[cc++] = t * 2;
    if (lv1 < val) loc[cc++] = t * 2 + 1;
    cntS[t] = cc;
    __syncthreads();
    if (t == 0) {
      int run = 0;
      for (int i = 0; i < NT; ++i) { int c2 = cntS[i]; cntS[i] = run; run += c2; }
      cntS[NT] = run;
    }
    __syncthreads();
    int base = cntS[t];
    for (int j = 0; j < cc; ++j)
      if (base + j < 31) p.heal_row[base + j] = loc[j];
    __syncthreads();
    if (t == 0) {
      int c = cntS[NT]; if (c > 31) c = 31;
      p.heal_row[31] = c;
      stUi(p.heals_done, 1);
      if (c > 0) {
        int r0 = p.heal_row[0];
        int best = 0; float bv = p.logits[r0 * V];
        for (int v = 1; v < BOSX; ++v) {
          float x = p.logits[r0 * V + v];
          if (x > bv) { bv = x; best = v; }
        }
        stUi(&p.lat[r0 + 1], best);
      }
    }
  }
  barFull(cnt, b);  // inv: drops all phase-A K/V lines from every L2/L1

  // ================= HEAL: barrier-free row pipeline, cached K/V reads ======
  int c = p.heal_row[31];
  int split = (c > 0) ? (p.heal_row[0] + 1) : L;
  for (int r = split + wg; r < L; r += NWG) {
    int nh = 0, hk = -1;
    for (int j = 0; j < c; ++j) {
      nh += (p.heal_row[j] < r) ? 1 : 0;
      if (j >= 1 && p.heal_row[j] == r) hk = j;
    }
    if (t == 0) {
      while (ldUi(p.heals_done) < nh) __builtin_amdgcn_s_sleep(1);
      cntS[0] = ldUi(&p.lat[r]);
    }
    __syncthreads();
    int tok = cntS[0];
    if (t < D) hS[0][t] = p.emb[tok * D + t] + p.pos[r * D + t];
    __syncthreads();
    lnorm(p.ln1_s, p.ln1_b, hS[0], xnS, redS);
    qkvPub<true>(p, 0, r, split, xnS, qS[0]);
    for (int l = 0; l < NLAYER; ++l) {
      attnProjFFN(p, r, l, hS[0], qS[0], oS, xnS, fS, padS, redS);
      if (l < NLAYER - 1) {
        lnorm(p.ln1_s + (l+1)*D, p.ln1_b + (l+1)*D, hS[0], xnS, redS);
        qkvPub<true>(p, l + 1, r, split, xnS, qS[0]);
      } else {
        headRow<true>(p, r, hS[0], xnS, redS, padS, oS);
      }
    }
    if (hk >= 0 && t == 0) {
      int best = 0; float bv = oS[0];
      for (int v = 1; v < BOSX; ++v)
        if (oS[v] > bv) { bv = oS[v]; best = v; }
      stUi(&p.lat[r + 1], best);
      asm volatile("s_waitcnt vmcnt(0)" ::: "memory");
      stUi(p.heals_done, hk + 1);
    }
  }

  barFull(cnt, b);

  // ================= tokens out =================
  {
    int gid = wg * NT + t;
    if (gid < L) p.out_tok[gid] = (float)ldUi(&p.lat[gid + 1]);
  }
}

extern "C" void kernel_launch(void* const* d_in, const int* in_sizes, int n_in,
                              void* d_out, int out_size, void* d_ws, size_t ws_size,
                              hipStream_t stream) {
  P prm;
  prm.tokens = (const int*)d_in[0];
  prm.emb    = (const float*)d_in[1];
  prm.pos    = (const float*)d_in[2];
  prm.ln1_s  = (const float*)d_in[3];
  prm.ln1_b  = (const float*)d_in[4];
  prm.wqkv   = (const float*)d_in[5];
  prm.bqkv   = (const float*)d_in[6];
  prm.wo     = (const float*)d_in[7];
  prm.bo     = (const float*)d_in[8];
  prm.ln2_s  = (const float*)d_in[9];
  prm.ln2_b  = (const float*)d_in[10];
  prm.w1     = (const float*)d_in[11];
  prm.b1     = (const float*)d_in[12];
  prm.w2     = (const float*)d_in[13];
  prm.b2     = (const float*)d_in[14];
  prm.lnf_s  = (const float*)d_in[15];
  prm.lnf_b  = (const float*)d_in[16];
  prm.hw     = (const float*)d_in[17];
  prm.hb     = (const float*)d_in[18];

  float* ws = (float*)d_ws;
  prm.kc   = ws;                            // NLAYER*L*D
  prm.vc   = prm.kc + (size_t)NLAYER*L*D;   // NLAYER*L*D
  prm.ll_  = prm.vc + (size_t)NLAYER*L*D;   // L
  prm.lat        = (int*)(prm.ll_ + L);     // 1025 (pad 1032)
  prm.heal_row   = prm.lat + 1032;          // 32 ([31] = count)
  prm.barc       = prm.heal_row + 32;       // 64
  prm.done       = prm.barc + 64;           // NLAYER*L
  prm.heals_done = prm.done + NLAYER * L;   // 16

  prm.logits  = (float*)d_out;              // L*V
  prm.out_tok = prm.logits + L * V;         // L

  kInit<<<64, 256, 0, stream>>>(prm.tokens, prm.lat, prm.barc, prm.done, prm.heals_done);

  void* args[] = { &prm };
  (void)hipLaunchCooperativeKernel((const void*)kMega, dim3(NWG), dim3(NT), args, 0, stream);
}